// Round 21
// baseline (158.839 us; speedup 1.0000x reference)
//
#include <hip/hip_runtime.h>

typedef __attribute__((ext_vector_type(8))) short s16x8;
typedef __attribute__((ext_vector_type(4))) float f32x4;

constexpr int B_ = 16;
constexpr int L_ = 4096;
constexpr int F_ = 512;
constexpr int H_ = 512;
constexpr int CT = 32;           // chunk length along L (proven shape)
constexpr int NC = L_ / CT;      // 128 chunks
constexpr int KC = 32;           // chunks per block (ls split: 4 x 32 = 128)
constexpr int NLS = NC / KC;     // 4 L-splits -> grid (4,4,16) = 256 blocks = 1/CU
constexpr int XROW = 520;        // padded LDS row (ushorts): 1040B rows

constexpr size_t WSOUT_OFF   = (size_t)9 << 20;                 // after Bp + E
constexpr size_t WSOUT_BYTES = (size_t)B_ * L_ * H_ * 2;        // 67.1 MB bf16

// Native bf16 cast: clang lowers to v_cvt_pk_bf16_f32 (RNE), pairing adjacent
// converts — R20 win (+8us VALU vs manual bit-twiddle RNE).
static __device__ __forceinline__ unsigned short f2bf(float f) {
  union { __bf16 b; unsigned short u; } v;
  v.b = (__bf16)f;
  return v.u;
}
static __device__ __forceinline__ float bf2f(unsigned short s) {
  union { unsigned u; float f; } v; v.u = ((unsigned)s) << 16;
  return v.f;
}

// ---------------- Kernel 1: pack B_real/B_img into MFMA B-fragment order (bf16) ----
__global__ void bprep_kernel(const float* __restrict__ BR, const float* __restrict__ BI,
                             s16x8* __restrict__ BpR, s16x8* __restrict__ BpI) {
  int ht = blockIdx.x >> 4;   // 0..31
  int fk = blockIdx.x & 15;   // 0..15
  int l  = threadIdx.x;       // 0..63
  int h  = ht * 16 + (l & 15);
  int f0 = fk * 32 + (l >> 4) * 8;
  s16x8 r, im;
#pragma unroll
  for (int j = 0; j < 8; ++j) {
    r[j]  = (short)f2bf(BR[(size_t)(f0 + j) * H_ + h]);
    im[j] = (short)f2bf(BI[(size_t)(f0 + j) * H_ + h]);
  }
  int idx = (ht * 16 + fk) * 64 + l;
  BpR[idx] = r;
  BpI[idx] = im;
}

// ---------------- Kernel 2: fused GEMM (bf16 MFMA) + in-register scan -------------
// grid: (ls=4, hq=4, b=16) = 256 blocks (1/CU); block: 512 threads (8 waves).
// R20 structure verbatim (register-resident B, one h-tile/wave, single LDS buffer,
// setprio, butterfly scan, native cvt). Only change: KC 16->32 (per-block preamble
// amortized 2x; Bp L2 traffic 131->66 MB; grid exactly one block per CU).
template <bool FUSED>
__global__ __launch_bounds__(512, 1) void gemm_scan_kernel(
    const float* __restrict__ x,
    const s16x8* __restrict__ BpR, const s16x8* __restrict__ BpI,
    const float* __restrict__ nu, const float* __restrict__ theta,
    const float* __restrict__ delta,
    float* __restrict__ out, unsigned short* __restrict__ wsout,
    float* __restrict__ ER, float* __restrict__ EI) {
  __shared__ __align__(16) unsigned short xs[CT * XROW];   // 33280 B

  const int ls   = blockIdx.x;   // 0..NLS-1 (L split: chunks ls*KC .. ls*KC+KC-1)
  const int hq   = blockIdx.y;   // 0..3  (h split: ht = hq*8 + w)
  const int b    = blockIdx.z;   // 0..B_-1
  const int tid  = threadIdx.x;
  const int lane = tid & 63;
  const int w    = tid >> 6;     // wave id 0..7
  const int g    = lane >> 4;    // lane group 0..3 (t sub-rows)
  const int cl   = lane & 15;    // column within 16-h tile

  const int ht = hq * 8 + w;     // this wave's h-tile 0..31
  const int h  = ht * 16 + cl;   // this thread's h

  // ---- load this wave's B fragments ONCE (register/AGPR-resident) ----
  s16x8 Brg[16], Big[16];
#pragma unroll
  for (int fk = 0; fk < 16; ++fk) {
    Brg[fk] = BpR[(ht * 16 + fk) * 64 + lane];
    Big[fk] = BpI[(ht * 16 + fk) * 64 + lane];
  }

  // ---- per-h scan parameters (once per block) ----
  const float dl = delta[h];
  const float mag = __expf(-__expf(nu[h]));
  const float thv = theta[h];
  const float lr = mag * __cosf(thv), li = mag * __sinf(thv);
  const float l2r = lr*lr - li*li,     l2i = 2.f*lr*li;
  const float l3r = l2r*lr - l2i*li,   l3i = l2r*li + l2i*lr;
  const float l4r = l2r*l2r - l2i*l2i, l4i = 2.f*l2r*l2i;
  const float l8r = l4r*l4r - l4i*l4i, l8i = 2.f*l4r*l4i;
  const float l12r = l8r*l4r - l8i*l4i, l12i = l8r*l4i + l8i*l4r;
  const float l16r = l8r*l8r - l8i*l8i, l16i = 2.f*l8r*l8i;
  const float m4r = (g==0)?1.f:((g==1)?l4r:((g==2)?l8r:l12r));
  const float m4i = (g==0)?0.f:((g==1)?l4i:((g==2)?l8i:l12i));

  const float* xbase = x + (size_t)(b * L_ + ls * KC * CT) * F_;

  // ---- prologue: load chunk 0 into registers ----
  float4 pv[4][2];
#pragma unroll
  for (int i = 0; i < 4; ++i) {
    int row = i * 8 + w;
    pv[i][0] = *(const float4*)(xbase + (size_t)row * F_ + lane * 8);
    pv[i][1] = *(const float4*)(xbase + (size_t)row * F_ + lane * 8 + 4);
  }

#pragma unroll 1
  for (int k = 0; k < KC; ++k) {
    __syncthreads();   // prior chunk's MFMA reads of xs complete (no-op at k=0)

    // ---- convert + write staged chunk k into LDS (proven layout) ----
#pragma unroll
    for (int i = 0; i < 4; ++i) {
      int row = i * 8 + w;
      s16x8 pk;
      pk[0] = (short)f2bf(pv[i][0].x); pk[1] = (short)f2bf(pv[i][0].y);
      pk[2] = (short)f2bf(pv[i][0].z); pk[3] = (short)f2bf(pv[i][0].w);
      pk[4] = (short)f2bf(pv[i][1].x); pk[5] = (short)f2bf(pv[i][1].y);
      pk[6] = (short)f2bf(pv[i][1].z); pk[7] = (short)f2bf(pv[i][1].w);
      *(s16x8*)(&xs[row * XROW + lane * 8]) = pk;
    }
    __syncthreads();

    // ---- issue next chunk's global loads (hide under MFMA + scan) ----
    if (k + 1 < KC) {
      const float* xq = xbase + (size_t)(k + 1) * CT * F_;
#pragma unroll
      for (int i = 0; i < 4; ++i) {
        int row = i * 8 + w;
        pv[i][0] = *(const float4*)(xq + (size_t)row * F_ + lane * 8);
        pv[i][1] = *(const float4*)(xq + (size_t)row * F_ + lane * 8 + 4);
      }
    }

    // ---- MFMA GEMM: 32 t-rows x 16 h (this wave); B from registers ----
    f32x4 accR[2], accI[2];   // [tt]
#pragma unroll
    for (int tt = 0; tt < 2; ++tt) {
      accR[tt] = (f32x4){0.f, 0.f, 0.f, 0.f};
      accI[tt] = (f32x4){0.f, 0.f, 0.f, 0.f};
    }
    __builtin_amdgcn_s_setprio(1);   // T5: favor MFMA-issuing wave on this SIMD
#pragma unroll
    for (int fk = 0; fk < 16; ++fk) {
      s16x8 a[2];
#pragma unroll
      for (int tt = 0; tt < 2; ++tt)
        a[tt] = *(const s16x8*)(&xs[(tt * 16 + cl) * XROW + fk * 32 + g * 8]);
#pragma unroll
      for (int tt = 0; tt < 2; ++tt) {
        accR[tt] = __builtin_amdgcn_mfma_f32_16x16x32_bf16(a[tt], Brg[fk], accR[tt], 0, 0, 0);
        accI[tt] = __builtin_amdgcn_mfma_f32_16x16x32_bf16(a[tt], Big[fk], accI[tt], 0, 0, 0);
      }
    }
    __builtin_amdgcn_s_setprio(0);

    // ---- in-register scan over t (butterfly cross-lane; proven R19/R20 body) ----
    const int c = ls * KC + k;
    {
      float carryR = 0.f, carryI = 0.f;   // chunk-local state (zero init)
      float* opf = out + (size_t)(b * L_ + c * CT) * H_ + h;
      unsigned short* opw = FUSED ? (wsout + (size_t)(b * L_ + c * CT) * H_ + h) : nullptr;

#pragma unroll
      for (int tt = 0; tt < 2; ++tt) {
        float lsR[4], lsI[4];
        float sR = 0.f, sI = 0.f;
#pragma unroll
        for (int r = 0; r < 4; ++r) {
          float uR = dl * accR[tt][r], uI = dl * accI[tt][r];
          float nR = lr * sR - li * sI + uR;
          float nI = lr * sI + li * sR + uI;
          sR = nR; sI = nI; lsR[r] = sR; lsI[r] = sI;
        }
        // butterfly step 1: exchange pair sums (groups 2q <-> 2q+1)
        float xR = __shfl_xor(sR, 16, 64);
        float xI = __shfl_xor(sI, 16, 64);
        const bool odd = (g & 1) != 0;
        float plR = odd ? xR : sR,  plI = odd ? xI : sI;   // s_{2q}
        float phR = odd ? sR : xR,  phI = odd ? sI : xI;   // s_{2q+1}
        float PR = l4r * plR - l4i * plI + phR;            // pair aggregate
        float PI = l4r * plI + l4i * plR + phI;
        // butterfly step 2: exchange pair aggregates (pairs 01 <-> 23)
        float yR = __shfl_xor(PR, 32, 64);
        float yI = __shfl_xor(PI, 32, 64);
        const bool hiq = (g >= 2);
        float P01R = hiq ? yR : PR,  P01I = hiq ? yI : PI;
        float P23R = hiq ? PR : yR,  P23I = hiq ? PI : yI;
        float TR = l8r * P01R - l8i * P01I + P23R;         // full inclusive
        float TI = l8r * P01I + l8i * P01R + P23I;
        // exclusive prefix e_g: {0, s0, P01, lam^4*P01 + s2}
        float zR = l4r * P01R - l4i * P01I + plR;
        float zI = l4r * P01I + l4i * P01R + plI;
        float eR = (g == 0) ? 0.f : (g == 1) ? plR : (g == 2) ? P01R : zR;
        float eI = (g == 0) ? 0.f : (g == 1) ? plI : (g == 2) ? P01I : zI;
        // incoming state for this lane's group: lam4^g * carry + e
        float incR = m4r * carryR - m4i * carryI + eR;
        float incI = m4r * carryI + m4i * carryR + eI;
        {
          float o0 = lsR[0] + lr  * incR - li  * incI;
          float o1 = lsR[1] + l2r * incR - l2i * incI;
          float o2 = lsR[2] + l3r * incR - l3i * incI;
          float o3 = lsR[3] + l4r * incR - l4i * incI;
          if (FUSED) {
            opw[(size_t)(tt * 16 + g * 4 + 0) * H_] = f2bf(o0);
            opw[(size_t)(tt * 16 + g * 4 + 1) * H_] = f2bf(o1);
            opw[(size_t)(tt * 16 + g * 4 + 2) * H_] = f2bf(o2);
            opw[(size_t)(tt * 16 + g * 4 + 3) * H_] = f2bf(o3);
          } else {
            opf[(size_t)(tt * 16 + g * 4 + 0) * H_] = o0;
            opf[(size_t)(tt * 16 + g * 4 + 1) * H_] = o1;
            opf[(size_t)(tt * 16 + g * 4 + 2) * H_] = o2;
            opf[(size_t)(tt * 16 + g * 4 + 3) * H_] = o3;
          }
        }
        // carry across tt: full inclusive + lam^16 * carry
        float ncR = TR + l16r * carryR - l16i * carryI;
        float ncI = TI + l16r * carryI + l16i * carryR;
        carryR = ncR; carryI = ncI;
      }
      if (g == 0) {
        size_t eidx = (size_t)(b * NC + c) * H_ + h;
        ER[eidx] = carryR;
        EI[eidx] = carryI;
      }
    }
  }
}

// ---------------- Kernel 3: chunk-level combine (E -> H0 in place), verbatim ------
__global__ void combine_kernel(const float* __restrict__ nu, const float* __restrict__ theta,
                               const float* __restrict__ h0r, const float* __restrict__ h0i,
                               float* __restrict__ ER, float* __restrict__ EI) {
  int gg = blockIdx.x * blockDim.x + threadIdx.x;   // 0..8191
  int b = gg >> 9;
  int h = gg & (H_ - 1);
  float mag = __expf(-__expf(nu[h]));
  float lr  = mag * __cosf(theta[h]);
  float li  = mag * __sinf(theta[h]);
  float pr = lr, pi = li;
#pragma unroll
  for (int s = 0; s < 5; ++s) {          // lam^32
    float nr = pr * pr - pi * pi;
    float ni = 2.f * pr * pi;
    pr = nr; pi = ni;
  }
  float sR = h0r[h], sI = h0i[h];
  for (int c0 = 0; c0 < NC; c0 += 8) {
    float tR[8], tI[8];
#pragma unroll
    for (int k = 0; k < 8; ++k) {
      size_t idx = (size_t)(b * NC + c0 + k) * H_ + h;
      tR[k] = ER[idx]; tI[k] = EI[idx];
    }
#pragma unroll
    for (int k = 0; k < 8; ++k) {
      size_t idx = (size_t)(b * NC + c0 + k) * H_ + h;
      ER[idx] = sR; EI[idx] = sI;     // becomes H0_c
      float nR = pr * sR - pi * sI + tR[k];
      float nI = pr * sI + pi * sR + tI[k];
      sR = nR; sI = nI;
    }
  }
}

// ---------------- Kernel 4a: legacy fixup out += Re(lam^{k+1} * H0_c) ------------
__global__ void fixup_kernel(const float* __restrict__ nu, const float* __restrict__ theta,
                             const float* __restrict__ ER, const float* __restrict__ EI,
                             float* __restrict__ out) {
  int c = blockIdx.x, b = blockIdx.y;
  int h = threadIdx.x;   // 512
  size_t idx = (size_t)(b * NC + c) * H_ + h;
  float hR = ER[idx], hI = EI[idx];
  float mag = __expf(-__expf(nu[h]));
  float lr  = mag * __cosf(theta[h]);
  float li  = mag * __sinf(theta[h]);
  float pr = lr, pi = li;
  float* op = out + (size_t)(b * L_ + c * CT) * H_ + h;
#pragma unroll 4
  for (int k = 0; k < CT; ++k) {
    op[(size_t)k * H_] += pr * hR - pi * hI;
    float nr = pr * lr - pi * li;
    float ni = pr * li + pi * lr;
    pr = nr; pi = ni;
  }
}

// ---------------- Kernel 4b: fused fixup out = bf16(local) + Re(lam^{k+1}*H0_c) ---
__global__ void fixup_fused_kernel(const float* __restrict__ nu, const float* __restrict__ theta,
                                   const float* __restrict__ ER, const float* __restrict__ EI,
                                   const unsigned short* __restrict__ wsout,
                                   float* __restrict__ out) {
  int c = blockIdx.x, b = blockIdx.y;
  int h = threadIdx.x;   // 512
  size_t idx = (size_t)(b * NC + c) * H_ + h;
  float hR = ER[idx], hI = EI[idx];
  float mag = __expf(-__expf(nu[h]));
  float lr  = mag * __cosf(theta[h]);
  float li  = mag * __sinf(theta[h]);
  float pr = lr, pi = li;
  size_t base = (size_t)(b * L_ + c * CT) * H_ + h;
  const unsigned short* wp = wsout + base;
  float* op = out + base;
#pragma unroll 4
  for (int k = 0; k < CT; ++k) {
    op[(size_t)k * H_] = bf2f(wp[(size_t)k * H_]) + (pr * hR - pi * hI);
    float nr = pr * lr - pi * li;
    float ni = pr * li + pi * lr;
    pr = nr; pi = ni;
  }
}

extern "C" void kernel_launch(void* const* d_in, const int* in_sizes, int n_in,
                              void* d_out, int out_size, void* d_ws, size_t ws_size,
                              hipStream_t stream) {
  const float* x   = (const float*)d_in[0];
  const float* BR  = (const float*)d_in[1];
  const float* BI  = (const float*)d_in[2];
  const float* nu  = (const float*)d_in[3];
  const float* th  = (const float*)d_in[4];
  const float* dl  = (const float*)d_in[5];
  const float* h0r = (const float*)d_in[6];
  const float* h0i = (const float*)d_in[7];
  float* out = (float*)d_out;

  char* wsc = (char*)d_ws;
  s16x8* BpR = (s16x8*)(wsc);
  s16x8* BpI = (s16x8*)(wsc + (512 << 10));
  float* ER  = (float*)(wsc + (1 << 20));
  float* EI  = (float*)(wsc + (1 << 20) + (size_t)B_ * NC * H_ * 4);
  unsigned short* wsout = (unsigned short*)(wsc + WSOUT_OFF);
  const bool fused = ws_size >= WSOUT_OFF + WSOUT_BYTES;

  hipLaunchKernelGGL(bprep_kernel, dim3(512), dim3(64), 0, stream, BR, BI, BpR, BpI);
  if (fused) {
    hipLaunchKernelGGL((gemm_scan_kernel<true>), dim3(NLS, 4, B_), dim3(512), 0, stream,
                       x, BpR, BpI, nu, th, dl, out, wsout, ER, EI);
    hipLaunchKernelGGL(combine_kernel, dim3(16), dim3(512), 0, stream, nu, th, h0r, h0i, ER, EI);
    hipLaunchKernelGGL(fixup_fused_kernel, dim3(NC, B_), dim3(512), 0, stream,
                       nu, th, ER, EI, wsout, out);
  } else {
    hipLaunchKernelGGL((gemm_scan_kernel<false>), dim3(NLS, 4, B_), dim3(512), 0, stream,
                       x, BpR, BpI, nu, th, dl, out, wsout, ER, EI);
    hipLaunchKernelGGL(combine_kernel, dim3(16), dim3(512), 0, stream, nu, th, h0r, h0i, ER, EI);
    hipLaunchKernelGGL(fixup_kernel, dim3(NC, B_), dim3(512), 0, stream, nu, th, ER, EI, out);
  }
}

// Round 22
// 152.010 us; speedup vs baseline: 1.0449x; 1.0449x over previous
//
#include <hip/hip_runtime.h>

typedef __attribute__((ext_vector_type(8))) short s16x8;
typedef __attribute__((ext_vector_type(4))) float f32x4;

constexpr int B_ = 16;
constexpr int L_ = 4096;
constexpr int F_ = 512;
constexpr int H_ = 512;
constexpr int CT = 32;           // chunk length along L (proven shape)
constexpr int NC = L_ / CT;      // 128 chunks
constexpr int KC = 16;           // chunks per block (ls split: 8 x 16 = 128)
                                 // KC=32 regressed (R21: FETCH 74->133MB, hq-dup
                                 // x reads stop being L2-absorbed at 1 block/CU)
constexpr int NLS = NC / KC;     // 8 L-splits -> grid (8,4,16) = 512 blocks
constexpr int XROW = 520;        // padded LDS row (ushorts): 1040B rows

constexpr size_t WSOUT_OFF   = (size_t)9 << 20;                 // after Bp + E
constexpr size_t WSOUT_BYTES = (size_t)B_ * L_ * H_ * 2;        // 67.1 MB bf16

// Native bf16 cast: clang lowers to v_cvt_pk_bf16_f32 (RNE), pairing adjacent
// converts — R20 win (-8us VALU vs manual bit-twiddle RNE).
static __device__ __forceinline__ unsigned short f2bf(float f) {
  union { __bf16 b; unsigned short u; } v;
  v.b = (__bf16)f;
  return v.u;
}
static __device__ __forceinline__ float bf2f(unsigned short s) {
  union { unsigned u; float f; } v; v.u = ((unsigned)s) << 16;
  return v.f;
}

// ---------------- Kernel 1: pack B_real/B_img into MFMA B-fragment order (bf16) ----
__global__ void bprep_kernel(const float* __restrict__ BR, const float* __restrict__ BI,
                             s16x8* __restrict__ BpR, s16x8* __restrict__ BpI) {
  int ht = blockIdx.x >> 4;   // 0..31
  int fk = blockIdx.x & 15;   // 0..15
  int l  = threadIdx.x;       // 0..63
  int h  = ht * 16 + (l & 15);
  int f0 = fk * 32 + (l >> 4) * 8;
  s16x8 r, im;
#pragma unroll
  for (int j = 0; j < 8; ++j) {
    r[j]  = (short)f2bf(BR[(size_t)(f0 + j) * H_ + h]);
    im[j] = (short)f2bf(BI[(size_t)(f0 + j) * H_ + h]);
  }
  int idx = (ht * 16 + fk) * 64 + l;
  BpR[idx] = r;
  BpI[idx] = im;
}

// ---------------- Kernel 2: fused GEMM (bf16 MFMA) + in-register scan -------------
// grid: (ls=8, hq=4, b=16) = 512 blocks (2/CU); block: 512 threads (8 waves).
// Champion R20 structure: register-resident B (one h-tile/wave), single LDS
// buffer, setprio around MFMA, butterfly scan, native bf16 cvt, FUSED bf16 out.
template <bool FUSED>
__global__ __launch_bounds__(512, 1) void gemm_scan_kernel(
    const float* __restrict__ x,
    const s16x8* __restrict__ BpR, const s16x8* __restrict__ BpI,
    const float* __restrict__ nu, const float* __restrict__ theta,
    const float* __restrict__ delta,
    float* __restrict__ out, unsigned short* __restrict__ wsout,
    float* __restrict__ ER, float* __restrict__ EI) {
  __shared__ __align__(16) unsigned short xs[CT * XROW];   // 33280 B

  const int ls   = blockIdx.x;   // 0..NLS-1 (L split: chunks ls*KC .. ls*KC+KC-1)
  const int hq   = blockIdx.y;   // 0..3  (h split: ht = hq*8 + w)
  const int b    = blockIdx.z;   // 0..B_-1
  const int tid  = threadIdx.x;
  const int lane = tid & 63;
  const int w    = tid >> 6;     // wave id 0..7
  const int g    = lane >> 4;    // lane group 0..3 (t sub-rows)
  const int cl   = lane & 15;    // column within 16-h tile

  const int ht = hq * 8 + w;     // this wave's h-tile 0..31
  const int h  = ht * 16 + cl;   // this thread's h

  // ---- load this wave's B fragments ONCE (register/AGPR-resident) ----
  s16x8 Brg[16], Big[16];
#pragma unroll
  for (int fk = 0; fk < 16; ++fk) {
    Brg[fk] = BpR[(ht * 16 + fk) * 64 + lane];
    Big[fk] = BpI[(ht * 16 + fk) * 64 + lane];
  }

  // ---- per-h scan parameters (once per block) ----
  const float dl = delta[h];
  const float mag = __expf(-__expf(nu[h]));
  const float thv = theta[h];
  const float lr = mag * __cosf(thv), li = mag * __sinf(thv);
  const float l2r = lr*lr - li*li,     l2i = 2.f*lr*li;
  const float l3r = l2r*lr - l2i*li,   l3i = l2r*li + l2i*lr;
  const float l4r = l2r*l2r - l2i*l2i, l4i = 2.f*l2r*l2i;
  const float l8r = l4r*l4r - l4i*l4i, l8i = 2.f*l4r*l4i;
  const float l12r = l8r*l4r - l8i*l4i, l12i = l8r*l4i + l8i*l4r;
  const float l16r = l8r*l8r - l8i*l8i, l16i = 2.f*l8r*l8i;
  const float m4r = (g==0)?1.f:((g==1)?l4r:((g==2)?l8r:l12r));
  const float m4i = (g==0)?0.f:((g==1)?l4i:((g==2)?l8i:l12i));

  const float* xbase = x + (size_t)(b * L_ + ls * KC * CT) * F_;

  // ---- prologue: load chunk 0 into registers ----
  float4 pv[4][2];
#pragma unroll
  for (int i = 0; i < 4; ++i) {
    int row = i * 8 + w;
    pv[i][0] = *(const float4*)(xbase + (size_t)row * F_ + lane * 8);
    pv[i][1] = *(const float4*)(xbase + (size_t)row * F_ + lane * 8 + 4);
  }

#pragma unroll 1
  for (int k = 0; k < KC; ++k) {
    __syncthreads();   // prior chunk's MFMA reads of xs complete (no-op at k=0)

    // ---- convert + write staged chunk k into LDS (proven layout) ----
#pragma unroll
    for (int i = 0; i < 4; ++i) {
      int row = i * 8 + w;
      s16x8 pk;
      pk[0] = (short)f2bf(pv[i][0].x); pk[1] = (short)f2bf(pv[i][0].y);
      pk[2] = (short)f2bf(pv[i][0].z); pk[3] = (short)f2bf(pv[i][0].w);
      pk[4] = (short)f2bf(pv[i][1].x); pk[5] = (short)f2bf(pv[i][1].y);
      pk[6] = (short)f2bf(pv[i][1].z); pk[7] = (short)f2bf(pv[i][1].w);
      *(s16x8*)(&xs[row * XROW + lane * 8]) = pk;
    }
    __syncthreads();

    // ---- issue next chunk's global loads (hide under MFMA + scan) ----
    if (k + 1 < KC) {
      const float* xq = xbase + (size_t)(k + 1) * CT * F_;
#pragma unroll
      for (int i = 0; i < 4; ++i) {
        int row = i * 8 + w;
        pv[i][0] = *(const float4*)(xq + (size_t)row * F_ + lane * 8);
        pv[i][1] = *(const float4*)(xq + (size_t)row * F_ + lane * 8 + 4);
      }
    }

    // ---- MFMA GEMM: 32 t-rows x 16 h (this wave); B from registers ----
    f32x4 accR[2], accI[2];   // [tt]
#pragma unroll
    for (int tt = 0; tt < 2; ++tt) {
      accR[tt] = (f32x4){0.f, 0.f, 0.f, 0.f};
      accI[tt] = (f32x4){0.f, 0.f, 0.f, 0.f};
    }
    __builtin_amdgcn_s_setprio(1);   // T5: favor MFMA-issuing wave on this SIMD
#pragma unroll
    for (int fk = 0; fk < 16; ++fk) {
      s16x8 a[2];
#pragma unroll
      for (int tt = 0; tt < 2; ++tt)
        a[tt] = *(const s16x8*)(&xs[(tt * 16 + cl) * XROW + fk * 32 + g * 8]);
#pragma unroll
      for (int tt = 0; tt < 2; ++tt) {
        accR[tt] = __builtin_amdgcn_mfma_f32_16x16x32_bf16(a[tt], Brg[fk], accR[tt], 0, 0, 0);
        accI[tt] = __builtin_amdgcn_mfma_f32_16x16x32_bf16(a[tt], Big[fk], accI[tt], 0, 0, 0);
      }
    }
    __builtin_amdgcn_s_setprio(0);

    // ---- in-register scan over t (butterfly cross-lane; proven R19/R20 body) ----
    const int c = ls * KC + k;
    {
      float carryR = 0.f, carryI = 0.f;   // chunk-local state (zero init)
      float* opf = out + (size_t)(b * L_ + c * CT) * H_ + h;
      unsigned short* opw = FUSED ? (wsout + (size_t)(b * L_ + c * CT) * H_ + h) : nullptr;

#pragma unroll
      for (int tt = 0; tt < 2; ++tt) {
        float lsR[4], lsI[4];
        float sR = 0.f, sI = 0.f;
#pragma unroll
        for (int r = 0; r < 4; ++r) {
          float uR = dl * accR[tt][r], uI = dl * accI[tt][r];
          float nR = lr * sR - li * sI + uR;
          float nI = lr * sI + li * sR + uI;
          sR = nR; sI = nI; lsR[r] = sR; lsI[r] = sI;
        }
        // butterfly step 1: exchange pair sums (groups 2q <-> 2q+1)
        float xR = __shfl_xor(sR, 16, 64);
        float xI = __shfl_xor(sI, 16, 64);
        const bool odd = (g & 1) != 0;
        float plR = odd ? xR : sR,  plI = odd ? xI : sI;   // s_{2q}
        float phR = odd ? sR : xR,  phI = odd ? sI : xI;   // s_{2q+1}
        float PR = l4r * plR - l4i * plI + phR;            // pair aggregate
        float PI = l4r * plI + l4i * plR + phI;
        // butterfly step 2: exchange pair aggregates (pairs 01 <-> 23)
        float yR = __shfl_xor(PR, 32, 64);
        float yI = __shfl_xor(PI, 32, 64);
        const bool hiq = (g >= 2);
        float P01R = hiq ? yR : PR,  P01I = hiq ? yI : PI;
        float P23R = hiq ? PR : yR,  P23I = hiq ? PI : yI;
        float TR = l8r * P01R - l8i * P01I + P23R;         // full inclusive
        float TI = l8r * P01I + l8i * P01R + P23I;
        // exclusive prefix e_g: {0, s0, P01, lam^4*P01 + s2}
        float zR = l4r * P01R - l4i * P01I + plR;
        float zI = l4r * P01I + l4i * P01R + plI;
        float eR = (g == 0) ? 0.f : (g == 1) ? plR : (g == 2) ? P01R : zR;
        float eI = (g == 0) ? 0.f : (g == 1) ? plI : (g == 2) ? P01I : zI;
        // incoming state for this lane's group: lam4^g * carry + e
        float incR = m4r * carryR - m4i * carryI + eR;
        float incI = m4r * carryI + m4i * carryR + eI;
        {
          float o0 = lsR[0] + lr  * incR - li  * incI;
          float o1 = lsR[1] + l2r * incR - l2i * incI;
          float o2 = lsR[2] + l3r * incR - l3i * incI;
          float o3 = lsR[3] + l4r * incR - l4i * incI;
          if (FUSED) {
            opw[(size_t)(tt * 16 + g * 4 + 0) * H_] = f2bf(o0);
            opw[(size_t)(tt * 16 + g * 4 + 1) * H_] = f2bf(o1);
            opw[(size_t)(tt * 16 + g * 4 + 2) * H_] = f2bf(o2);
            opw[(size_t)(tt * 16 + g * 4 + 3) * H_] = f2bf(o3);
          } else {
            opf[(size_t)(tt * 16 + g * 4 + 0) * H_] = o0;
            opf[(size_t)(tt * 16 + g * 4 + 1) * H_] = o1;
            opf[(size_t)(tt * 16 + g * 4 + 2) * H_] = o2;
            opf[(size_t)(tt * 16 + g * 4 + 3) * H_] = o3;
          }
        }
        // carry across tt: full inclusive + lam^16 * carry
        float ncR = TR + l16r * carryR - l16i * carryI;
        float ncI = TI + l16r * carryI + l16i * carryR;
        carryR = ncR; carryI = ncI;
      }
      if (g == 0) {
        size_t eidx = (size_t)(b * NC + c) * H_ + h;
        ER[eidx] = carryR;
        EI[eidx] = carryI;
      }
    }
  }
}

// ---------------- Kernel 3: chunk-level combine (E -> H0 in place), verbatim ------
__global__ void combine_kernel(const float* __restrict__ nu, const float* __restrict__ theta,
                               const float* __restrict__ h0r, const float* __restrict__ h0i,
                               float* __restrict__ ER, float* __restrict__ EI) {
  int gg = blockIdx.x * blockDim.x + threadIdx.x;   // 0..8191
  int b = gg >> 9;
  int h = gg & (H_ - 1);
  float mag = __expf(-__expf(nu[h]));
  float lr  = mag * __cosf(theta[h]);
  float li  = mag * __sinf(theta[h]);
  float pr = lr, pi = li;
#pragma unroll
  for (int s = 0; s < 5; ++s) {          // lam^32
    float nr = pr * pr - pi * pi;
    float ni = 2.f * pr * pi;
    pr = nr; pi = ni;
  }
  float sR = h0r[h], sI = h0i[h];
  for (int c0 = 0; c0 < NC; c0 += 8) {
    float tR[8], tI[8];
#pragma unroll
    for (int k = 0; k < 8; ++k) {
      size_t idx = (size_t)(b * NC + c0 + k) * H_ + h;
      tR[k] = ER[idx]; tI[k] = EI[idx];
    }
#pragma unroll
    for (int k = 0; k < 8; ++k) {
      size_t idx = (size_t)(b * NC + c0 + k) * H_ + h;
      ER[idx] = sR; EI[idx] = sI;     // becomes H0_c
      float nR = pr * sR - pi * sI + tR[k];
      float nI = pr * sI + pi * sR + tI[k];
      sR = nR; sI = nI;
    }
  }
}

// ---------------- Kernel 4a: legacy fixup out += Re(lam^{k+1} * H0_c) ------------
__global__ void fixup_kernel(const float* __restrict__ nu, const float* __restrict__ theta,
                             const float* __restrict__ ER, const float* __restrict__ EI,
                             float* __restrict__ out) {
  int c = blockIdx.x, b = blockIdx.y;
  int h = threadIdx.x;   // 512
  size_t idx = (size_t)(b * NC + c) * H_ + h;
  float hR = ER[idx], hI = EI[idx];
  float mag = __expf(-__expf(nu[h]));
  float lr  = mag * __cosf(theta[h]);
  float li  = mag * __sinf(theta[h]);
  float pr = lr, pi = li;
  float* op = out + (size_t)(b * L_ + c * CT) * H_ + h;
#pragma unroll 4
  for (int k = 0; k < CT; ++k) {
    op[(size_t)k * H_] += pr * hR - pi * hI;
    float nr = pr * lr - pi * li;
    float ni = pr * li + pi * lr;
    pr = nr; pi = ni;
  }
}

// ---------------- Kernel 4b: fused fixup out = bf16(local) + Re(lam^{k+1}*H0_c) ---
__global__ void fixup_fused_kernel(const float* __restrict__ nu, const float* __restrict__ theta,
                                   const float* __restrict__ ER, const float* __restrict__ EI,
                                   const unsigned short* __restrict__ wsout,
                                   float* __restrict__ out) {
  int c = blockIdx.x, b = blockIdx.y;
  int h = threadIdx.x;   // 512
  size_t idx = (size_t)(b * NC + c) * H_ + h;
  float hR = ER[idx], hI = EI[idx];
  float mag = __expf(-__expf(nu[h]));
  float lr  = mag * __cosf(theta[h]);
  float li  = mag * __sinf(theta[h]);
  float pr = lr, pi = li;
  size_t base = (size_t)(b * L_ + c * CT) * H_ + h;
  const unsigned short* wp = wsout + base;
  float* op = out + base;
#pragma unroll 4
  for (int k = 0; k < CT; ++k) {
    op[(size_t)k * H_] = bf2f(wp[(size_t)k * H_]) + (pr * hR - pi * hI);
    float nr = pr * lr - pi * li;
    float ni = pr * li + pi * lr;
    pr = nr; pi = ni;
  }
}

extern "C" void kernel_launch(void* const* d_in, const int* in_sizes, int n_in,
                              void* d_out, int out_size, void* d_ws, size_t ws_size,
                              hipStream_t stream) {
  const float* x   = (const float*)d_in[0];
  const float* BR  = (const float*)d_in[1];
  const float* BI  = (const float*)d_in[2];
  const float* nu  = (const float*)d_in[3];
  const float* th  = (const float*)d_in[4];
  const float* dl  = (const float*)d_in[5];
  const float* h0r = (const float*)d_in[6];
  const float* h0i = (const float*)d_in[7];
  float* out = (float*)d_out;

  char* wsc = (char*)d_ws;
  s16x8* BpR = (s16x8*)(wsc);
  s16x8* BpI = (s16x8*)(wsc + (512 << 10));
  float* ER  = (float*)(wsc + (1 << 20));
  float* EI  = (float*)(wsc + (1 << 20) + (size_t)B_ * NC * H_ * 4);
  unsigned short* wsout = (unsigned short*)(wsc + WSOUT_OFF);
  const bool fused = ws_size >= WSOUT_OFF + WSOUT_BYTES;

  hipLaunchKernelGGL(bprep_kernel, dim3(512), dim3(64), 0, stream, BR, BI, BpR, BpI);
  if (fused) {
    hipLaunchKernelGGL((gemm_scan_kernel<true>), dim3(NLS, 4, B_), dim3(512), 0, stream,
                       x, BpR, BpI, nu, th, dl, out, wsout, ER, EI);
    hipLaunchKernelGGL(combine_kernel, dim3(16), dim3(512), 0, stream, nu, th, h0r, h0i, ER, EI);
    hipLaunchKernelGGL(fixup_fused_kernel, dim3(NC, B_), dim3(512), 0, stream,
                       nu, th, ER, EI, wsout, out);
  } else {
    hipLaunchKernelGGL((gemm_scan_kernel<false>), dim3(NLS, 4, B_), dim3(512), 0, stream,
                       x, BpR, BpI, nu, th, dl, out, wsout, ER, EI);
    hipLaunchKernelGGL(combine_kernel, dim3(16), dim3(512), 0, stream, nu, th, h0r, h0i, ER, EI);
    hipLaunchKernelGGL(fixup_kernel, dim3(NC, B_), dim3(512), 0, stream, nu, th, ER, EI, out);
  }
}